// Round 10
// baseline (188.364 us; speedup 1.0000x reference)
//
#include <hip/hip_runtime.h>
#include <math.h>

// Problem sizes (fixed by the reference)
constexpr int B_ = 4, S_ = 1024, E_ = 128, H_ = 16, DK_ = 8, F_ = 512;
constexpr int R_ = B_ * S_; // 4096 token rows
#define EPSV 1e-5f

// Workspace layout (float offsets).
constexpr int OFF_WQT  = 0;
constexpr int OFF_WOT  = OFF_WQT + E_ * E_;     // 16384
constexpr int OFF_W2T  = OFF_WOT + E_ * E_;     // 32768
constexpr int OFF_QCB  = OFF_W2T + F_ * E_;     // 98304   (bf16 Q/K [64][1024][8], 1 MB)
constexpr int OFF_VTB  = OFF_QCB + 262144;      // 360448  (bf16 V^T [64][8][1024], 1 MB)
constexpr int OFF_X1   = OFF_QCB;               // reuse (qcb/vtb dead after attn)
constexpr int OFF_CTX  = OFF_VTB + 262144;      // 622592
constexpr int OFF_QOUT = OFF_CTX + R_ * E_;     // 1146880
// total ws ≈ 4.7 MB

typedef __attribute__((ext_vector_type(4)))  short short4v;
typedef __attribute__((ext_vector_type(8)))  short short8v;
typedef __attribute__((ext_vector_type(16))) float f32x16;

static __device__ __forceinline__ void fma4(float4& acc, float s, const float4 v) {
    acc.x = fmaf(s, v.x, acc.x);
    acc.y = fmaf(s, v.y, acc.y);
    acc.z = fmaf(s, v.z, acc.z);
    acc.w = fmaf(s, v.w, acc.w);
}

static __device__ __forceinline__ short4v pack2(unsigned a, unsigned b) {
    union { unsigned u[2]; short4v s; } t;
    t.u[0] = a; t.u[1] = b;
    return t.s;
}

// 4× f32 -> 4× bf16 (RNE) via hardware cvt_pk
static __device__ __forceinline__ short4v cvt4_bf16(float a, float b, float c, float d) {
    unsigned p0, p1;
    asm("v_cvt_pk_bf16_f32 %0, %1, %2" : "=v"(p0) : "v"(a), "v"(b));
    asm("v_cvt_pk_bf16_f32 %0, %1, %2" : "=v"(p1) : "v"(c), "v"(d));
    return pack2(p0, p1);
}

// --------------------------------------------- transpose via 32x32 LDS tiles
// grid 96: tiles 0..15 Wq, 16..31 Wo, 32..95 W2. Coalesced reads AND writes.
__global__ __launch_bounds__(256) void k_transpose(const float* __restrict__ Wq,
                                                   const float* __restrict__ Wo,
                                                   const float* __restrict__ W2,
                                                   float* __restrict__ ws) {
    __shared__ float ts[32][33];
    const int t = blockIdx.x, tid = threadIdx.x;
    const float* src; float* dst; int lds_, ldd, r0s, c0s;
    if (t < 16)      { src = Wq; dst = ws + OFF_WQT; lds_ = 128; ldd = 128;
                       r0s = (t & 3) * 32;        c0s = (t >> 2) * 32; }
    else if (t < 32) { int u = t - 16; src = Wo; dst = ws + OFF_WOT; lds_ = 128; ldd = 128;
                       r0s = (u & 3) * 32;        c0s = (u >> 2) * 32; }
    else             { int u = t - 32; src = W2; dst = ws + OFF_W2T; lds_ = 512; ldd = 128;
                       r0s = (u & 3) * 32;        c0s = (u >> 2) * 32; }
    const int rr = tid >> 3, cc = (tid & 7) * 4;
    const float4 v = *(const float4*)(src + (r0s + rr) * lds_ + c0s + cc);
    ts[rr][cc + 0] = v.x; ts[rr][cc + 1] = v.y;
    ts[rr][cc + 2] = v.z; ts[rr][cc + 3] = v.w;
    __syncthreads();
    float4 o;
    o.x = ts[cc + 0][rr]; o.y = ts[cc + 1][rr];
    o.z = ts[cc + 2][rr]; o.w = ts[cc + 3][rr];
    *(float4*)(dst + (c0s + rr) * ldd + r0s + cc) = o;
}

// ------------------------------------------------- q projection + cos(+rx)
// 16 rows/block, thread = 2 rows x 4 cols. grid 256.
// Emits bf16 qcb[bh][s][8]; vtb[b*128+e][s] via LDS transpose (coalesced).
__global__ __launch_bounds__(256) void k_qproj(const float* __restrict__ x,
                                               const float* __restrict__ bq,
                                               const float* __restrict__ rx,
                                               const float* __restrict__ WqT,
                                               short* __restrict__ qcb,
                                               short* __restrict__ vtb) {
    __shared__ __attribute__((aligned(16))) float xs[16][128];  // 8 KB
    __shared__ __attribute__((aligned(16))) short vts[128][20]; // 5 KB (pad: 2-way max)
    const int tid = threadIdx.x;
    const int row0 = blockIdx.x * 16;
    {
        const float4* src = (const float4*)(x + row0 * E_);
        ((float4*)xs)[tid]       = src[tid];
        ((float4*)xs)[tid + 256] = src[tid + 256];
    }
    __syncthreads();
    const int cg = tid & 31, rg = tid >> 5;
    const int c0 = cg * 4, r0 = rg * 2;
    const float* wp = WqT + c0;
    float4 a0 = {0.f,0.f,0.f,0.f}, a1 = {0.f,0.f,0.f,0.f};
#pragma unroll 4
    for (int k0 = 0; k0 < 128; k0 += 4) {
        const float4 w0 = *(const float4*)(wp + (k0 + 0) * 128);
        const float4 w1 = *(const float4*)(wp + (k0 + 1) * 128);
        const float4 w2 = *(const float4*)(wp + (k0 + 2) * 128);
        const float4 w3 = *(const float4*)(wp + (k0 + 3) * 128);
        const float4 u0 = *(const float4*)&xs[r0][k0];
        const float4 u1 = *(const float4*)&xs[r0 + 1][k0];
        fma4(a0, u0.x, w0); fma4(a1, u1.x, w0);
        fma4(a0, u0.y, w1); fma4(a1, u1.y, w1);
        fma4(a0, u0.z, w2); fma4(a1, u1.z, w2);
        fma4(a0, u0.w, w3); fma4(a1, u1.w, w3);
    }
    const float4 bb = *(const float4*)(bq + c0);
    const float4 rr = *(const float4*)(rx + c0);
    const int b = row0 >> 10, sB = row0 & 1023;
    const int h = c0 >> 3, d0 = c0 & 7;
    const int bh = b * H_ + h;
    float4 o0, o1;
    o0.x = cosf(a0.x + bb.x + rr.x); o0.y = cosf(a0.y + bb.y + rr.y);
    o0.z = cosf(a0.z + bb.z + rr.z); o0.w = cosf(a0.w + bb.w + rr.w);
    o1.x = cosf(a1.x + bb.x + rr.x); o1.y = cosf(a1.y + bb.y + rr.y);
    o1.z = cosf(a1.z + bb.z + rr.z); o1.w = cosf(a1.w + bb.w + rr.w);
    const short4v q0 = cvt4_bf16(o0.x, o0.y, o0.z, o0.w);
    const short4v q1 = cvt4_bf16(o1.x, o1.y, o1.z, o1.w);
    *(short4v*)(qcb + (size_t)(bh * S_ + sB + r0) * 8 + d0)     = q0;
    *(short4v*)(qcb + (size_t)(bh * S_ + sB + r0 + 1) * 8 + d0) = q1;
    vts[c0 + 0][r0] = q0[0]; vts[c0 + 1][r0] = q0[1];
    vts[c0 + 2][r0] = q0[2]; vts[c0 + 3][r0] = q0[3];
    vts[c0 + 0][r0 + 1] = q1[0]; vts[c0 + 1][r0 + 1] = q1[1];
    vts[c0 + 2][r0 + 1] = q1[2]; vts[c0 + 3][r0 + 1] = q1[3];
    __syncthreads();
    // vtb row (b*128 + e) gets 16 s-values; 256 threads write 16 B each.
    const int e = tid >> 1, hf = tid & 1;
    short8v vv;
#pragma unroll
    for (int j = 0; j < 8; ++j) vv[j] = vts[e][hf * 8 + j];
    *(short8v*)(vtb + (size_t)(b * 128 + e) * S_ + sB + hf * 8) = vv;
}

// ---------------------------------------------------------------- attention
// MFMA flash-style, no max subtraction (|scores| <= 2.83). (validated r8)
__global__ __launch_bounds__(256) void k_attn(const short* __restrict__ qcb,
                                              const short* __restrict__ vtb,
                                              float* __restrict__ ctx) {
    constexpr float SC = 0.35355339059327373f;
    const int tid = threadIdx.x;
    const int bh = blockIdx.x >> 3;
    const int qt = blockIdx.x & 7;
    const int lane = tid & 63;
    const int row = lane & 31, hi = lane >> 5;
    const int q0 = qt * 128 + (tid >> 6) * 32;

    const short4v qfrag = *(const short4v*)(qcb + (size_t)(bh * S_ + q0 + row) * 8 + 4 * hi);
    const short* kb = qcb + (size_t)bh * S_ * 8 + 4 * hi;
    const bool vok = row < 8;
    const short* vb = vtb + (size_t)(bh * 8 + (row & 7)) * S_ + 4 * hi;
    const short4v zf = {0, 0, 0, 0};

    f32x16 pacc = {0,0,0,0,0,0,0,0,0,0,0,0,0,0,0,0};
    const f32x16 zacc = {0,0,0,0,0,0,0,0,0,0,0,0,0,0,0,0};
    float lsum = 0.f;

#pragma unroll 2
    for (int tk = 0; tk < S_; tk += 32) {
        const short4v kfrag = *(const short4v*)(kb + (size_t)(tk + row) * 8);
        f32x16 sd = __builtin_amdgcn_mfma_f32_32x32x8bf16_1k(kfrag, qfrag, zacc, 0, 0, 0);

        short4v pb0, pb1, pb2, pb3;
#define PCHUNK(c, pbv) { \
        const float e0 = __expf(sd[4*(c)+0] * SC); \
        const float e1 = __expf(sd[4*(c)+1] * SC); \
        const float e2 = __expf(sd[4*(c)+2] * SC); \
        const float e3 = __expf(sd[4*(c)+3] * SC); \
        lsum += (e0 + e1) + (e2 + e3); \
        pbv = cvt4_bf16(e0, e1, e2, e3); }
        PCHUNK(0, pb0)
        PCHUNK(1, pb1)
        PCHUNK(2, pb2)
        PCHUNK(3, pb3)
#undef PCHUNK

        const short4v v0 = vok ? *(const short4v*)(vb + tk +  0) : zf;
        const short4v v1 = vok ? *(const short4v*)(vb + tk +  8) : zf;
        const short4v v2 = vok ? *(const short4v*)(vb + tk + 16) : zf;
        const short4v v3 = vok ? *(const short4v*)(vb + tk + 24) : zf;
        pacc = __builtin_amdgcn_mfma_f32_32x32x8bf16_1k(v0, pb0, pacc, 0, 0, 0);
        pacc = __builtin_amdgcn_mfma_f32_32x32x8bf16_1k(v1, pb1, pacc, 0, 0, 0);
        pacc = __builtin_amdgcn_mfma_f32_32x32x8bf16_1k(v2, pb2, pacc, 0, 0, 0);
        pacc = __builtin_amdgcn_mfma_f32_32x32x8bf16_1k(v3, pb3, pacc, 0, 0, 0);
    }

    lsum += __shfl_xor(lsum, 32);
    const float inv = 1.0f / lsum;
    const int b = bh >> 4, h = bh & 15;
    float4 o;
    o.x = pacc[0] * inv; o.y = pacc[1] * inv;
    o.z = pacc[2] * inv; o.w = pacc[3] * inv;
    *(float4*)(ctx + (size_t)(b * S_ + q0 + row) * E_ + h * 8 + 4 * hi) = o;
}

// ----------------------------------- ctx@Wo^T + bo + x -> LN1 -> x1, qout
// 16 rows/block, thread = 2 rows x 4 cols, LN via 32-lane shuffle. grid 256.
__global__ __launch_bounds__(256) void k_oproj_ln1(const float* __restrict__ ctx,
                                                   const float* __restrict__ WoT,
                                                   const float* __restrict__ bo,
                                                   const float* __restrict__ x,
                                                   const float* __restrict__ g1,
                                                   const float* __restrict__ bln1,
                                                   const float* __restrict__ ry,
                                                   float* __restrict__ x1,
                                                   float* __restrict__ qout) {
    __shared__ __attribute__((aligned(16))) float cs[16][128]; // 8 KB
    const int tid = threadIdx.x;
    const int row0 = blockIdx.x * 16;
    {
        const float4* src = (const float4*)(ctx + row0 * E_);
        ((float4*)cs)[tid]       = src[tid];
        ((float4*)cs)[tid + 256] = src[tid + 256];
    }
    __syncthreads();
    const int cg = tid & 31, rg = tid >> 5;
    const int c0 = cg * 4, r0 = rg * 2;
    const float* wp = WoT + c0;
    float4 a0 = {0.f,0.f,0.f,0.f}, a1 = {0.f,0.f,0.f,0.f};
#pragma unroll 4
    for (int k0 = 0; k0 < 128; k0 += 4) {
        const float4 w0 = *(const float4*)(wp + (k0 + 0) * 128);
        const float4 w1 = *(const float4*)(wp + (k0 + 1) * 128);
        const float4 w2 = *(const float4*)(wp + (k0 + 2) * 128);
        const float4 w3 = *(const float4*)(wp + (k0 + 3) * 128);
        const float4 u0 = *(const float4*)&cs[r0][k0];
        const float4 u1 = *(const float4*)&cs[r0 + 1][k0];
        fma4(a0, u0.x, w0); fma4(a1, u1.x, w0);
        fma4(a0, u0.y, w1); fma4(a1, u1.y, w1);
        fma4(a0, u0.z, w2); fma4(a1, u1.z, w2);
        fma4(a0, u0.w, w3); fma4(a1, u1.w, w3);
    }
    const int gr0 = row0 + r0, gr1 = gr0 + 1;
    const float4 bb = *(const float4*)(bo + c0);
    const float4 xa = *(const float4*)(x + gr0 * E_ + c0);
    const float4 xb = *(const float4*)(x + gr1 * E_ + c0);
    float4 y0, y1;
    y0.x = a0.x + bb.x + xa.x; y0.y = a0.y + bb.y + xa.y;
    y0.z = a0.z + bb.z + xa.z; y0.w = a0.w + bb.w + xa.w;
    y1.x = a1.x + bb.x + xb.x; y1.y = a1.y + bb.y + xb.y;
    y1.z = a1.z + bb.z + xb.z; y1.w = a1.w + bb.w + xb.w;
    float s0 = (y0.x + y0.y) + (y0.z + y0.w);
    float q0 = fmaf(y0.x, y0.x, y0.y * y0.y) + fmaf(y0.z, y0.z, y0.w * y0.w);
    float s1 = (y1.x + y1.y) + (y1.z + y1.w);
    float q1 = fmaf(y1.x, y1.x, y1.y * y1.y) + fmaf(y1.z, y1.z, y1.w * y1.w);
#pragma unroll
    for (int m = 1; m < 32; m <<= 1) {
        s0 += __shfl_xor(s0, m); q0 += __shfl_xor(q0, m);
        s1 += __shfl_xor(s1, m); q1 += __shfl_xor(q1, m);
    }
    const float mu0 = s0 * (1.0f / 128.0f);
    const float is0 = rsqrtf(q0 * (1.0f / 128.0f) - mu0 * mu0 + EPSV);
    const float mu1 = s1 * (1.0f / 128.0f);
    const float is1 = rsqrtf(q1 * (1.0f / 128.0f) - mu1 * mu1 + EPSV);
    const float4 gg = *(const float4*)(g1 + c0);
    const float4 lb = *(const float4*)(bln1 + c0);
    float4 o0, o1;
    o0.x = (y0.x - mu0) * is0 * gg.x + lb.x;
    o0.y = (y0.y - mu0) * is0 * gg.y + lb.y;
    o0.z = (y0.z - mu0) * is0 * gg.z + lb.z;
    o0.w = (y0.w - mu0) * is0 * gg.w + lb.w;
    o1.x = (y1.x - mu1) * is1 * gg.x + lb.x;
    o1.y = (y1.y - mu1) * is1 * gg.y + lb.y;
    o1.z = (y1.z - mu1) * is1 * gg.z + lb.z;
    o1.w = (y1.w - mu1) * is1 * gg.w + lb.w;
    *(float4*)(x1 + gr0 * E_ + c0) = o0;
    *(float4*)(x1 + gr1 * E_ + c0) = o1;
    if (c0 < 8) {
        float4 qo0, qo1;
        qo0.x = cosf(o0.x) * cosf(ry[c0 + 0]);
        qo0.y = cosf(o0.y) * cosf(ry[c0 + 1]);
        qo0.z = cosf(o0.z) * cosf(ry[c0 + 2]);
        qo0.w = cosf(o0.w) * cosf(ry[c0 + 3]);
        qo1.x = cosf(o1.x) * cosf(ry[c0 + 0]);
        qo1.y = cosf(o1.y) * cosf(ry[c0 + 1]);
        qo1.z = cosf(o1.z) * cosf(ry[c0 + 2]);
        qo1.w = cosf(o1.w) * cosf(ry[c0 + 3]);
        *(float4*)(qout + gr0 * 8 + c0) = qo0;
        *(float4*)(qout + gr1 * 8 + c0) = qo1;
    }
}

// ------------------------- FFN (relu(qout@W1^T+b1)@W2^T+b2) + res + LN2
// 16 rows/block, thread = 2 rows x 4 cols. h1 tile 16x512 f32 (32 KB). grid 256.
__global__ __launch_bounds__(256) void k_ffn_ln2(const float* __restrict__ qout,
                                                 const float* __restrict__ W1,
                                                 const float* __restrict__ b1,
                                                 const float* __restrict__ W2T,
                                                 const float* __restrict__ b2,
                                                 const float* __restrict__ x1,
                                                 const float* __restrict__ g2,
                                                 const float* __restrict__ bln2,
                                                 float* __restrict__ out) {
    __shared__ __attribute__((aligned(16))) float qs[16][8];   // 0.5 KB
    __shared__ __attribute__((aligned(16))) float h1[16][512]; // 32 KB
    const int tid = threadIdx.x;
    const int row0 = blockIdx.x * 16;
    if (tid < 32) ((float4*)qs)[tid] = ((const float4*)(qout + row0 * 8))[tid];
    __syncthreads();
#pragma unroll
    for (int i = 0; i < 32; ++i) {
        const int f = ((i & 1) << 8) + tid;
        const int r = i >> 1;                     // uniform per iteration
        const float4 wa = *(const float4*)(W1 + f * 8);
        const float4 wb = *(const float4*)(W1 + f * 8 + 4);
        float v = b1[f];
        v = fmaf(qs[r][0], wa.x, v); v = fmaf(qs[r][1], wa.y, v);
        v = fmaf(qs[r][2], wa.z, v); v = fmaf(qs[r][3], wa.w, v);
        v = fmaf(qs[r][4], wb.x, v); v = fmaf(qs[r][5], wb.y, v);
        v = fmaf(qs[r][6], wb.z, v); v = fmaf(qs[r][7], wb.w, v);
        h1[r][f] = fmaxf(v, 0.0f);
    }
    __syncthreads();
    const int cg = tid & 31, rg = tid >> 5;
    const int c0 = cg * 4, r0 = rg * 2;
    const float* wp = W2T + c0;
    float4 a0 = {0.f,0.f,0.f,0.f}, a1 = {0.f,0.f,0.f,0.f};
#pragma unroll 4
    for (int f0 = 0; f0 < 512; f0 += 4) {
        const float4 w0 = *(const float4*)(wp + (f0 + 0) * 128);
        const float4 w1 = *(const float4*)(wp + (f0 + 1) * 128);
        const float4 w2 = *(const float4*)(wp + (f0 + 2) * 128);
        const float4 w3 = *(const float4*)(wp + (f0 + 3) * 128);
        const float4 u0 = *(const float4*)&h1[r0][f0];
        const float4 u1 = *(const float4*)&h1[r0 + 1][f0];
        fma4(a0, u0.x, w0); fma4(a1, u1.x, w0);
        fma4(a0, u0.y, w1); fma4(a1, u1.y, w1);
        fma4(a0, u0.z, w2); fma4(a1, u1.z, w2);
        fma4(a0, u0.w, w3); fma4(a1, u1.w, w3);
    }
    const int gr0 = row0 + r0, gr1 = gr0 + 1;
    const float4 bb = *(const float4*)(b2 + c0);
    const float4 xa = *(const float4*)(x1 + gr0 * E_ + c0);
    const float4 xb = *(const float4*)(x1 + gr1 * E_ + c0);
    float4 y0, y1;
    y0.x = a0.x + bb.x + xa.x; y0.y = a0.y + bb.y + xa.y;
    y0.z = a0.z + bb.z + xa.z; y0.w = a0.w + bb.w + xa.w;
    y1.x = a1.x + bb.x + xb.x; y1.y = a1.y + bb.y + xb.y;
    y1.z = a1.z + bb.z + xb.z; y1.w = a1.w + bb.w + xb.w;
    float s0 = (y0.x + y0.y) + (y0.z + y0.w);
    float q0 = fmaf(y0.x, y0.x, y0.y * y0.y) + fmaf(y0.z, y0.z, y0.w * y0.w);
    float s1 = (y1.x + y1.y) + (y1.z + y1.w);
    float q1 = fmaf(y1.x, y1.x, y1.y * y1.y) + fmaf(y1.z, y1.z, y1.w * y1.w);
#pragma unroll
    for (int m = 1; m < 32; m <<= 1) {
        s0 += __shfl_xor(s0, m); q0 += __shfl_xor(q0, m);
        s1 += __shfl_xor(s1, m); q1 += __shfl_xor(q1, m);
    }
    const float mu0 = s0 * (1.0f / 128.0f);
    const float is0 = rsqrtf(q0 * (1.0f / 128.0f) - mu0 * mu0 + EPSV);
    const float mu1 = s1 * (1.0f / 128.0f);
    const float is1 = rsqrtf(q1 * (1.0f / 128.0f) - mu1 * mu1 + EPSV);
    const float4 gg = *(const float4*)(g2 + c0);
    const float4 lb = *(const float4*)(bln2 + c0);
    float4 o0, o1;
    o0.x = (y0.x - mu0) * is0 * gg.x + lb.x;
    o0.y = (y0.y - mu0) * is0 * gg.y + lb.y;
    o0.z = (y0.z - mu0) * is0 * gg.z + lb.z;
    o0.w = (y0.w - mu0) * is0 * gg.w + lb.w;
    o1.x = (y1.x - mu1) * is1 * gg.x + lb.x;
    o1.y = (y1.y - mu1) * is1 * gg.y + lb.y;
    o1.z = (y1.z - mu1) * is1 * gg.z + lb.z;
    o1.w = (y1.w - mu1) * is1 * gg.w + lb.w;
    *(float4*)(out + gr0 * E_ + c0) = o0;
    *(float4*)(out + gr1 * E_ + c0) = o1;
}

extern "C" void kernel_launch(void* const* d_in, const int* in_sizes, int n_in,
                              void* d_out, int out_size, void* d_ws, size_t ws_size,
                              hipStream_t stream) {
    const float* x   = (const float*)d_in[0];
    const float* Wq  = (const float*)d_in[1];
    const float* bq  = (const float*)d_in[2];
    // d_in[3..6] = Wk, bk, Wv, bv : unused by the reference's output
    const float* rx  = (const float*)d_in[7];
    const float* Wo  = (const float*)d_in[8];
    const float* bo  = (const float*)d_in[9];
    const float* ry  = (const float*)d_in[10];
    const float* W1  = (const float*)d_in[11];
    const float* b1  = (const float*)d_in[12];
    const float* W2  = (const float*)d_in[13];
    const float* b2  = (const float*)d_in[14];
    const float* g1  = (const float*)d_in[15];
    const float* bl1 = (const float*)d_in[16];
    const float* g2  = (const float*)d_in[17];
    const float* bl2 = (const float*)d_in[18];
    float* ws  = (float*)d_ws;
    float* out = (float*)d_out;
    short* qcb = (short*)(ws + OFF_QCB);
    short* vtb = (short*)(ws + OFF_VTB);

    k_transpose<<<dim3(96), dim3(256), 0, stream>>>(Wq, Wo, W2, ws);
    k_qproj<<<dim3(R_ / 16), dim3(256), 0, stream>>>(x, bq, rx, ws + OFF_WQT, qcb, vtb);
    k_attn<<<dim3(B_ * H_ * 8), dim3(256), 0, stream>>>(qcb, vtb, ws + OFF_CTX);
    k_oproj_ln1<<<dim3(R_ / 16), dim3(256), 0, stream>>>(ws + OFF_CTX, ws + OFF_WOT, bo, x,
                                                         g1, bl1, ry,
                                                         ws + OFF_X1, ws + OFF_QOUT);
    k_ffn_ln2<<<dim3(R_ / 16), dim3(256), 0, stream>>>(ws + OFF_QOUT, W1, b1, ws + OFF_W2T,
                                                       b2, ws + OFF_X1, g2, bl2, out);
}

// Round 11
// 154.739 us; speedup vs baseline: 1.2173x; 1.2173x over previous
//
#include <hip/hip_runtime.h>
#include <math.h>

// Problem sizes (fixed by the reference)
constexpr int B_ = 4, S_ = 1024, E_ = 128, H_ = 16, DK_ = 8, F_ = 512;
constexpr int R_ = B_ * S_; // 4096 token rows
#define EPSV 1e-5f

// Workspace layout (bf16/short offsets).
constexpr size_t OFF_XB   = 0;                  // x    bf16 [4096][128]
constexpr size_t OFF_WQB  = OFF_XB   + 524288;  // Wq   bf16 [128][128] (original layout)
constexpr size_t OFF_WOB  = OFF_WQB  + 16384;   // Wo   bf16 [128][128]
constexpr size_t OFF_W1B  = OFF_WOB  + 16384;   // W1   bf16 [512][8]
constexpr size_t OFF_W2B  = OFF_W1B  + 4096;    // W2   bf16 [128][512]
constexpr size_t OFF_QCB  = OFF_W2B  + 65536;   // Q/K  bf16 [64][1024][8]
constexpr size_t OFF_VTB  = OFF_QCB  + 524288;  // V^T  bf16 [64][8][1024]
constexpr size_t OFF_CTXB = OFF_VTB  + 524288;  // ctx  bf16 [4096][128]
constexpr size_t OFF_X1B  = OFF_CTXB + 524288;  // x1   bf16 [4096][128]
constexpr size_t OFF_QOB  = OFF_X1B  + 524288;  // qout bf16 [4096][8]
// total ≈ 5.5 MB

typedef __attribute__((ext_vector_type(4)))  short short4v;
typedef __attribute__((ext_vector_type(8)))  short short8v;
typedef __attribute__((ext_vector_type(16))) float f32x16;

static __device__ __forceinline__ short4v pack2(unsigned a, unsigned b) {
    union { unsigned u[2]; short4v s; } t;
    t.u[0] = a; t.u[1] = b;
    return t.s;
}

// 4× f32 -> 4× bf16 (RNE) via hardware cvt_pk
static __device__ __forceinline__ short4v cvt4_bf16(float a, float b, float c, float d) {
    unsigned p0, p1;
    asm("v_cvt_pk_bf16_f32 %0, %1, %2" : "=v"(p0) : "v"(a), "v"(b));
    asm("v_cvt_pk_bf16_f32 %0, %1, %2" : "=v"(p1) : "v"(c), "v"(d));
    return pack2(p0, p1);
}

static __device__ __forceinline__ short8v cvt8_bf16(const float* v) {
    const short4v a = cvt4_bf16(v[0], v[1], v[2], v[3]);
    const short4v b = cvt4_bf16(v[4], v[5], v[6], v[7]);
    short8v r;
    r[0]=a[0]; r[1]=a[1]; r[2]=a[2]; r[3]=a[3];
    r[4]=b[0]; r[5]=b[1]; r[6]=b[2]; r[7]=b[3];
    return r;
}

static __device__ __forceinline__ float b2f(short v) {
    return __uint_as_float(((unsigned)(unsigned short)v) << 16);
}

// --------------------------------------------------- bf16 conversion (prep)
// float4 count ranges: x 131072 | Wq 4096 | Wo 4096 | W1 1024 | W2 16384
__global__ __launch_bounds__(256) void k_prep(const float* __restrict__ x,
                                              const float* __restrict__ Wq,
                                              const float* __restrict__ Wo,
                                              const float* __restrict__ W1,
                                              const float* __restrict__ W2,
                                              short* __restrict__ ws) {
    const int idx = blockIdx.x * 256 + threadIdx.x;
    const float* src; short* dst; int local;
    if (idx < 131072)      { src = x;  dst = ws + OFF_XB;  local = idx; }
    else if (idx < 135168) { src = Wq; dst = ws + OFF_WQB; local = idx - 131072; }
    else if (idx < 139264) { src = Wo; dst = ws + OFF_WOB; local = idx - 135168; }
    else if (idx < 140288) { src = W1; dst = ws + OFF_W1B; local = idx - 139264; }
    else                   { src = W2; dst = ws + OFF_W2B; local = idx - 140288; }
    const float4 v = ((const float4*)src)[local];
    ((short4v*)dst)[local] = cvt4_bf16(v.x, v.y, v.z, v.w);
}

// -------------------------------------------------- q projection via MFMA
// block = 4 waves; block tile 32 rows x 128 cols (wave w: cols w*32..+31).
// A-frag: xb[r0+row][k0+4hi+j]; B-frag: wqb[c][k0+4hi+j] (original Wq layout).
// D: col = lane&31, row = (reg&3)+8*(reg>>2)+4*hi. grid 128.
__global__ __launch_bounds__(256) void k_qproj(const short* __restrict__ xb,
                                               const float* __restrict__ bq,
                                               const float* __restrict__ rx,
                                               const short* __restrict__ wqb,
                                               short* __restrict__ qcb,
                                               short* __restrict__ vtb) {
    const int tid = threadIdx.x, lane = tid & 63, w = tid >> 6;
    const int row = lane & 31, hi = lane >> 5;
    const int r0 = blockIdx.x * 32;
    const int c  = w * 32 + row;
    const short* ap = xb  + (size_t)(r0 + row) * 128 + 4 * hi;
    const short* bp = wqb + (size_t)c * 128 + 4 * hi;
    f32x16 acc = {0,0,0,0,0,0,0,0,0,0,0,0,0,0,0,0};
#pragma unroll
    for (int k0 = 0; k0 < 128; k0 += 8) {
        const short4v af = *(const short4v*)(ap + k0);
        const short4v bf = *(const short4v*)(bp + k0);
        acc = __builtin_amdgcn_mfma_f32_32x32x8bf16_1k(af, bf, acc, 0, 0, 0);
    }
    const float add = bq[c] + rx[c];
    float cv[16];
#pragma unroll
    for (int i = 0; i < 16; ++i) cv[i] = cosf(acc[i] + add);
    const int b = r0 >> 10, sloc0 = r0 & 1023;
    const int h = c >> 3, d = c & 7;
    const int bh = b * H_ + h;
    short* qbase = qcb + ((size_t)bh * 1024 + sloc0) * 8 + d;
    short* vbase = vtb + ((size_t)bh * 8 + d) * 1024 + sloc0;
#pragma unroll
    for (int rq = 0; rq < 4; ++rq) {
        const short4v v = cvt4_bf16(cv[4*rq+0], cv[4*rq+1], cv[4*rq+2], cv[4*rq+3]);
        const int sb = 8 * rq + 4 * hi;  // local row of elem 0
        *(short4v*)(vbase + sb) = v;
        qbase[(sb + 0) * 8] = v[0];
        qbase[(sb + 1) * 8] = v[1];
        qbase[(sb + 2) * 8] = v[2];
        qbase[(sb + 3) * 8] = v[3];
    }
}

// ---------------------------------------------------------------- attention
// MFMA flash-style, no max subtraction (validated r8). Now emits bf16 ctx.
__global__ __launch_bounds__(256) void k_attn(const short* __restrict__ qcb,
                                              const short* __restrict__ vtb,
                                              short* __restrict__ ctxb) {
    constexpr float SC = 0.35355339059327373f;
    const int tid = threadIdx.x;
    const int bh = blockIdx.x >> 3;
    const int qt = blockIdx.x & 7;
    const int lane = tid & 63;
    const int row = lane & 31, hi = lane >> 5;
    const int q0 = qt * 128 + (tid >> 6) * 32;

    const short4v qfrag = *(const short4v*)(qcb + (size_t)(bh * S_ + q0 + row) * 8 + 4 * hi);
    const short* kb = qcb + (size_t)bh * S_ * 8 + 4 * hi;
    const bool vok = row < 8;
    const short* vb = vtb + (size_t)(bh * 8 + (row & 7)) * S_ + 4 * hi;
    const short4v zf = {0, 0, 0, 0};

    f32x16 pacc = {0,0,0,0,0,0,0,0,0,0,0,0,0,0,0,0};
    const f32x16 zacc = {0,0,0,0,0,0,0,0,0,0,0,0,0,0,0,0};
    float lsum = 0.f;

#pragma unroll 2
    for (int tk = 0; tk < S_; tk += 32) {
        const short4v kfrag = *(const short4v*)(kb + (size_t)(tk + row) * 8);
        f32x16 sd = __builtin_amdgcn_mfma_f32_32x32x8bf16_1k(kfrag, qfrag, zacc, 0, 0, 0);

        short4v pb0, pb1, pb2, pb3;
#define PCHUNK(c, pbv) { \
        const float e0 = __expf(sd[4*(c)+0] * SC); \
        const float e1 = __expf(sd[4*(c)+1] * SC); \
        const float e2 = __expf(sd[4*(c)+2] * SC); \
        const float e3 = __expf(sd[4*(c)+3] * SC); \
        lsum += (e0 + e1) + (e2 + e3); \
        pbv = cvt4_bf16(e0, e1, e2, e3); }
        PCHUNK(0, pb0)
        PCHUNK(1, pb1)
        PCHUNK(2, pb2)
        PCHUNK(3, pb3)
#undef PCHUNK

        const short4v v0 = vok ? *(const short4v*)(vb + tk +  0) : zf;
        const short4v v1 = vok ? *(const short4v*)(vb + tk +  8) : zf;
        const short4v v2 = vok ? *(const short4v*)(vb + tk + 16) : zf;
        const short4v v3 = vok ? *(const short4v*)(vb + tk + 24) : zf;
        pacc = __builtin_amdgcn_mfma_f32_32x32x8bf16_1k(v0, pb0, pacc, 0, 0, 0);
        pacc = __builtin_amdgcn_mfma_f32_32x32x8bf16_1k(v1, pb1, pacc, 0, 0, 0);
        pacc = __builtin_amdgcn_mfma_f32_32x32x8bf16_1k(v2, pb2, pacc, 0, 0, 0);
        pacc = __builtin_amdgcn_mfma_f32_32x32x8bf16_1k(v3, pb3, pacc, 0, 0, 0);
    }

    lsum += __shfl_xor(lsum, 32);
    const float inv = 1.0f / lsum;
    const int b = bh >> 4, h = bh & 15;
    const short4v co = cvt4_bf16(pacc[0] * inv, pacc[1] * inv,
                                 pacc[2] * inv, pacc[3] * inv);
    *(short4v*)(ctxb + (size_t)(b * S_ + q0 + row) * 128 + h * 8 + 4 * hi) = co;
}

// --------------------- ctx@Wo^T + bo + x -> LN1 -> x1 (bf16), qout (bf16)
// MFMA 32x128 block tile + LDS y-tile two-phase LN. grid 128.
__global__ __launch_bounds__(256) void k_oproj_ln1(const short* __restrict__ ctxb,
                                                   const short* __restrict__ wob,
                                                   const float* __restrict__ bo,
                                                   const float* __restrict__ x,
                                                   const float* __restrict__ g1,
                                                   const float* __restrict__ bln1,
                                                   const float* __restrict__ ry,
                                                   short* __restrict__ x1b,
                                                   short* __restrict__ qob) {
    __shared__ float yt[32][129];
    const int tid = threadIdx.x, lane = tid & 63, w = tid >> 6;
    const int row = lane & 31, hi = lane >> 5;
    const int r0 = blockIdx.x * 32;
    const int c  = w * 32 + row;
    const short* ap = ctxb + (size_t)(r0 + row) * 128 + 4 * hi;
    const short* bp = wob  + (size_t)c * 128 + 4 * hi;
    f32x16 acc = {0,0,0,0,0,0,0,0,0,0,0,0,0,0,0,0};
#pragma unroll
    for (int k0 = 0; k0 < 128; k0 += 8) {
        const short4v af = *(const short4v*)(ap + k0);
        const short4v bf = *(const short4v*)(bp + k0);
        acc = __builtin_amdgcn_mfma_f32_32x32x8bf16_1k(af, bf, acc, 0, 0, 0);
    }
    const float bov = bo[c];
#pragma unroll
    for (int i = 0; i < 16; ++i) {
        const int sl = (i & 3) + 8 * (i >> 2) + 4 * hi;
        yt[sl][c] = acc[i] + bov + x[(size_t)(r0 + sl) * 128 + c];
    }
    __syncthreads();
    const int rr = tid >> 3, cl = (tid & 7) * 16;
    float yv[16], s = 0.f, q = 0.f;
#pragma unroll
    for (int j = 0; j < 16; ++j) {
        const float v = yt[rr][cl + j];
        yv[j] = v; s += v; q = fmaf(v, v, q);
    }
#pragma unroll
    for (int m = 1; m < 8; m <<= 1) {
        s += __shfl_xor(s, m);
        q += __shfl_xor(q, m);
    }
    const float mu = s * (1.0f / 128.0f);
    const float is = rsqrtf(q * (1.0f / 128.0f) - mu * mu + EPSV);
    float ov[16];
#pragma unroll
    for (int j = 0; j < 16; ++j)
        ov[j] = (yv[j] - mu) * is * g1[cl + j] + bln1[cl + j];
    *(short8v*)(x1b + (size_t)(r0 + rr) * 128 + cl)     = cvt8_bf16(ov);
    *(short8v*)(x1b + (size_t)(r0 + rr) * 128 + cl + 8) = cvt8_bf16(ov + 8);
    if (cl == 0) {
        float qo[8];
#pragma unroll
        for (int j = 0; j < 8; ++j) qo[j] = cosf(ov[j]) * cosf(ry[j]);
        *(short8v*)(qob + (size_t)(r0 + rr) * 8) = cvt8_bf16(qo);
    }
}

// ---------------- FFN: relu(qout@W1^T+b1) -> LDS bf16 -> @W2^T + b2 + x1, LN2
// Stage1: k=8 single mfma per f-tile; Stage2: k=512 (64 mfma). grid 128.
__global__ __launch_bounds__(256) void k_ffn_ln2(const short* __restrict__ qob,
                                                 const short* __restrict__ w1b,
                                                 const float* __restrict__ b1,
                                                 const short* __restrict__ w2b,
                                                 const float* __restrict__ b2,
                                                 const short* __restrict__ x1b,
                                                 const float* __restrict__ g2,
                                                 const float* __restrict__ bln2,
                                                 float* __restrict__ out) {
    __shared__ short h1b[32][516];  // pad: 2-way max on stage-2 ds_read
    __shared__ float yt[32][129];
    const int tid = threadIdx.x, lane = tid & 63, w = tid >> 6;
    const int row = lane & 31, hi = lane >> 5;
    const int r0 = blockIdx.x * 32;
    const f32x16 zacc = {0,0,0,0,0,0,0,0,0,0,0,0,0,0,0,0};

    // ---- stage 1: h1[32][512]
    const short4v af1 = *(const short4v*)(qob + (size_t)(r0 + row) * 8 + 4 * hi);
#pragma unroll
    for (int it = 0; it < 4; ++it) {
        const int f = it * 128 + w * 32 + row;
        const short4v bf1 = *(const short4v*)(w1b + (size_t)f * 8 + 4 * hi);
        f32x16 a1 = __builtin_amdgcn_mfma_f32_32x32x8bf16_1k(af1, bf1, zacc, 0, 0, 0);
        const float bv = b1[f];
#pragma unroll
        for (int rq = 0; rq < 4; ++rq) {
            const short4v hv = cvt4_bf16(fmaxf(a1[4*rq+0] + bv, 0.f),
                                         fmaxf(a1[4*rq+1] + bv, 0.f),
                                         fmaxf(a1[4*rq+2] + bv, 0.f),
                                         fmaxf(a1[4*rq+3] + bv, 0.f));
            const int sb = 8 * rq + 4 * hi;
            h1b[sb + 0][f] = hv[0];
            h1b[sb + 1][f] = hv[1];
            h1b[sb + 2][f] = hv[2];
            h1b[sb + 3][f] = hv[3];
        }
    }
    __syncthreads();

    // ---- stage 2: C2 = h1 @ W2^T
    const int c = w * 32 + row;
    const short* ap2 = &h1b[row][4 * hi];
    const short* bp2 = w2b + (size_t)c * 512 + 4 * hi;
    f32x16 acc = zacc;
#pragma unroll 8
    for (int k0 = 0; k0 < 512; k0 += 8) {
        const short4v af = *(const short4v*)(ap2 + k0);
        const short4v bf = *(const short4v*)(bp2 + k0);
        acc = __builtin_amdgcn_mfma_f32_32x32x8bf16_1k(af, bf, acc, 0, 0, 0);
    }
    const float b2v = b2[c];
#pragma unroll
    for (int i = 0; i < 16; ++i) {
        const int sl = (i & 3) + 8 * (i >> 2) + 4 * hi;
        yt[sl][c] = acc[i] + b2v + b2f(x1b[(size_t)(r0 + sl) * 128 + c]);
    }
    __syncthreads();
    const int rr = tid >> 3, cl = (tid & 7) * 16;
    float yv[16], s = 0.f, q = 0.f;
#pragma unroll
    for (int j = 0; j < 16; ++j) {
        const float v = yt[rr][cl + j];
        yv[j] = v; s += v; q = fmaf(v, v, q);
    }
#pragma unroll
    for (int m = 1; m < 8; m <<= 1) {
        s += __shfl_xor(s, m);
        q += __shfl_xor(q, m);
    }
    const float mu = s * (1.0f / 128.0f);
    const float is = rsqrtf(q * (1.0f / 128.0f) - mu * mu + EPSV);
    float* op = out + (size_t)(r0 + rr) * 128 + cl;
#pragma unroll
    for (int jj = 0; jj < 4; ++jj) {
        float4 o;
        o.x = (yv[4*jj+0] - mu) * is * g2[cl + 4*jj + 0] + bln2[cl + 4*jj + 0];
        o.y = (yv[4*jj+1] - mu) * is * g2[cl + 4*jj + 1] + bln2[cl + 4*jj + 1];
        o.z = (yv[4*jj+2] - mu) * is * g2[cl + 4*jj + 2] + bln2[cl + 4*jj + 2];
        o.w = (yv[4*jj+3] - mu) * is * g2[cl + 4*jj + 3] + bln2[cl + 4*jj + 3];
        *(float4*)(op + 4 * jj) = o;
    }
}

extern "C" void kernel_launch(void* const* d_in, const int* in_sizes, int n_in,
                              void* d_out, int out_size, void* d_ws, size_t ws_size,
                              hipStream_t stream) {
    const float* x   = (const float*)d_in[0];
    const float* Wq  = (const float*)d_in[1];
    const float* bq  = (const float*)d_in[2];
    // d_in[3..6] = Wk, bk, Wv, bv : unused by the reference's output
    const float* rx  = (const float*)d_in[7];
    const float* Wo  = (const float*)d_in[8];
    const float* bo  = (const float*)d_in[9];
    const float* ry  = (const float*)d_in[10];
    const float* W1  = (const float*)d_in[11];
    const float* b1  = (const float*)d_in[12];
    const float* W2  = (const float*)d_in[13];
    const float* b2  = (const float*)d_in[14];
    const float* g1  = (const float*)d_in[15];
    const float* bl1 = (const float*)d_in[16];
    const float* g2  = (const float*)d_in[17];
    const float* bl2 = (const float*)d_in[18];
    short* ws  = (short*)d_ws;
    float* out = (float*)d_out;

    k_prep<<<dim3(612), dim3(256), 0, stream>>>(x, Wq, Wo, W1, W2, ws);
    k_qproj<<<dim3(R_ / 32), dim3(256), 0, stream>>>(ws + OFF_XB, bq, rx, ws + OFF_WQB,
                                                     ws + OFF_QCB, ws + OFF_VTB);
    k_attn<<<dim3(B_ * H_ * 8), dim3(256), 0, stream>>>(ws + OFF_QCB, ws + OFF_VTB,
                                                        ws + OFF_CTXB);
    k_oproj_ln1<<<dim3(R_ / 32), dim3(256), 0, stream>>>(ws + OFF_CTXB, ws + OFF_WOB, bo, x,
                                                         g1, bl1, ry,
                                                         ws + OFF_X1B, ws + OFF_QOB);
    k_ffn_ln2<<<dim3(R_ / 32), dim3(256), 0, stream>>>(ws + OFF_QOB, ws + OFF_W1B, b1,
                                                       ws + OFF_W2B, b2, ws + OFF_X1B,
                                                       g2, bl2, out);
}